// Round 9
// baseline (11313.197 us; speedup 1.0000x reference)
//
#include <hip/hip_runtime.h>
#include <cstdint>
#include <cstddef>

#define T_STEPS 2048
#define BATCH   32
#define VDIM    512
#define HDIM    512
#define SLICES  8      // WGs per batch element (scan)
#define COLS    64     // columns per scan WG
#define KPT     64     // k-range per scan wave
#define KCH     4      // chains (batch elements) interleaved per WG
#define BM      128    // GEMM rows per WG
#define BN      64     // GEMM cols per WG

typedef _Float16 half2v __attribute__((ext_vector_type(2)));
typedef _Float16 half8v __attribute__((ext_vector_type(8)));
typedef float    f32x4  __attribute__((ext_vector_type(4)));

__device__ __forceinline__ float dot2h(half2v a, half2v b, float c) {
#if __has_builtin(__builtin_amdgcn_fdot2)
    return __builtin_amdgcn_fdot2(a, b, c, false);
#else
    return fmaf((float)a.x, (float)b.x, fmaf((float)a.y, (float)b.y, c));
#endif
}

__device__ __forceinline__ unsigned long long loadt(const unsigned long long* p) {
    return __hip_atomic_load(p, __ATOMIC_RELAXED, __HIP_MEMORY_SCOPE_AGENT);
}
__device__ __forceinline__ void storet(unsigned long long* p, float v, unsigned tag) {
    unsigned long long x = ((unsigned long long)tag << 32) | (unsigned)__float_as_uint(v);
    __hip_atomic_store(p, x, __ATOMIC_RELAXED, __HIP_MEMORY_SCOPE_AGENT);
}

// ---------------- Phase 0: pack W -> k-packed f16 tiles (once per call) ----
__global__ __launch_bounds__(512)
void pack_b(const float* __restrict__ W0, const float* __restrict__ W1,
            const float* __restrict__ W2, _Float16* __restrict__ Bt)
{
    const int kg = blockIdx.x;
    const int g  = blockIdx.y;
    const float* W = (g == 0) ? W0 : (g == 1) ? W1 : W2;
    const int n = threadIdx.x;
    half8v v;
    #pragma unroll
    for (int i = 0; i < 8; ++i)
        v[i] = (_Float16)W[(size_t)(kg * 8 + i) * HDIM + n];
    *(half8v*)&Bt[((((size_t)g * 64 + kg) * 512) + n) * 8] = v;
}

// ---------------- Phase 1: fused-gate x-projection via f16 MFMA ----------
__global__ __launch_bounds__(256)
void xproj_mfma2(const float* __restrict__ X, const _Float16* __restrict__ Bt,
                 const float* __restrict__ b0, const float* __restrict__ b1,
                 const float* __restrict__ b2,
                 float* __restrict__ xp, int M)
{
    const int n0 = blockIdx.x * BN;
    const int m0 = blockIdx.y * BM;

    __shared__ __align__(16) _Float16 Blds[64 * 64 * 8];

    const int tid  = threadIdx.x;
    const int lane = tid & 63;
    const int w    = tid >> 6;
    const int r16  = lane & 15;
    const int kq   = lane >> 4;

    half8v a[2][16];
    #pragma unroll
    for (int ms = 0; ms < 2; ++ms) {
        const float* ap = X + (size_t)(m0 + 32 * w + 16 * ms + r16) * VDIM;
        #pragma unroll
        for (int ks = 0; ks < 16; ++ks) {
            const float* p = ap + ks * 32 + kq * 8;
            float4 x0 = *(const float4*)p;
            float4 x1 = *(const float4*)(p + 4);
            half8v v;
            v[0] = (_Float16)x0.x; v[1] = (_Float16)x0.y;
            v[2] = (_Float16)x0.z; v[3] = (_Float16)x0.w;
            v[4] = (_Float16)x1.x; v[5] = (_Float16)x1.y;
            v[6] = (_Float16)x1.z; v[7] = (_Float16)x1.w;
            a[ms][ks] = v;
        }
    }
    #pragma unroll
    for (int ms = 0; ms < 2; ++ms)
        #pragma unroll
        for (int ks = 0; ks < 16; ++ks)
            asm volatile("" : "+v"(a[ms][ks]));

    for (int g = 0; g < 3; ++g) {
        __syncthreads();
        {
            const _Float16* src = Bt + (((size_t)g * 64) * 512 + n0) * 8;
            const int c = tid & 63;
            #pragma unroll
            for (int it = 0; it < 16; ++it) {
                const int kg = (tid >> 6) + 4 * it;
                *(half8v*)&Blds[(size_t)(kg * 64 + c) * 8] =
                    *(const half8v*)&src[((size_t)kg * 512 + c) * 8];
            }
        }
        __syncthreads();

        f32x4 acc[2][4] = {};
        #pragma unroll
        for (int ks = 0; ks < 16; ++ks) {
            #pragma unroll
            for (int cb = 0; cb < 4; ++cb) {
                half8v bf = *(const half8v*)
                    &Blds[(size_t)((4 * ks + kq) * 64 + 16 * cb + r16) * 8];
                acc[0][cb] = __builtin_amdgcn_mfma_f32_16x16x32_f16(a[0][ks], bf, acc[0][cb], 0, 0, 0);
                acc[1][cb] = __builtin_amdgcn_mfma_f32_16x16x32_f16(a[1][ks], bf, acc[1][cb], 0, 0, 0);
            }
        }

        const float* bias = (g == 0) ? b0 : (g == 1) ? b1 : b2;
        float* out = xp + (size_t)g * M * HDIM;
        #pragma unroll
        for (int cb = 0; cb < 4; ++cb) {
            const float bb = bias[n0 + 16 * cb + r16];
            #pragma unroll
            for (int ms = 0; ms < 2; ++ms)
                #pragma unroll
                for (int r = 0; r < 4; ++r) {
                    const int row = m0 + 32 * w + 16 * ms + 4 * kq + r;
                    out[(size_t)row * HDIM + n0 + 16 * cb + r16] = acc[ms][cb][r] + bb;
                }
        }
    }
}

// ---------------- Phase 2: K-chain interleaved scan ----------------------
// Grid 64 WGs: g = blockIdx&7 (batch group: batches 4g..4g+3), s = blockIdx>>3
// (column slice). 512 threads: c = tid&63, jw = tid>>6 (k-slice wave).
// Wave i (i<KCH) additionally OWNS chain i: reduce, gates, publish, output.
// Per super-step: batch-issued polls for all 4 chains (loads in flight before
// checks) -> 4x dots -> 1 barrier -> parallel owner publishes; x2 phases.
// The 2 MALL round-trips per step are amortized over 4 independent chains.
__global__ __launch_bounds__(512)
__attribute__((amdgpu_waves_per_eu(2, 2)))
void gru_scan7(const float* __restrict__ xp,
               const float* __restrict__ Wrh, const float* __restrict__ Wnh,
               const float* __restrict__ Wzh,
               const float* __restrict__ state, float* __restrict__ out,
               unsigned long long* __restrict__ hT,
               unsigned long long* __restrict__ uT,
               int t0, int nt, int M)
{
    const int g   = blockIdx.x & 7;
    const int s   = blockIdx.x >> 3;
    const int tid = threadIdx.x;
    const int c   = tid & (COLS - 1);
    const int jw  = tid >> 6;              // k-slice wave AND (if <KCH) chain owner
    const int n   = s * COLS + c;

    __shared__ __align__(16) _Float16 hlds[KCH][HDIM];
    __shared__ __align__(16) _Float16 ulds[KCH][HDIM];
    __shared__ float redR[KCH][SLICES][COLS];
    __shared__ float redN[KCH][SLICES][COLS];
    __shared__ float redZ[KCH][SLICES][COLS];

    // ---- weights -> f16x2 registers (96 VGPRs), chain-invariant ----
    half2v w2r[KPT / 2], w2n[KPT / 2], w2z[KPT / 2];
    {
        const size_t coloff = (size_t)s * COLS + c;
        const float* pr = Wrh + (size_t)jw * KPT * HDIM + coloff;
        const float* pn = Wnh + (size_t)jw * KPT * HDIM + coloff;
        const float* pz = Wzh + (size_t)jw * KPT * HDIM + coloff;
        #pragma unroll
        for (int q = 0; q < KPT / 2; ++q) {
            half2v r, nn, z;
            r.x  = (_Float16)pr[(size_t)(2 * q) * HDIM];
            r.y  = (_Float16)pr[(size_t)(2 * q + 1) * HDIM];
            nn.x = (_Float16)pn[(size_t)(2 * q) * HDIM];
            nn.y = (_Float16)pn[(size_t)(2 * q + 1) * HDIM];
            z.x  = (_Float16)pz[(size_t)(2 * q) * HDIM];
            z.y  = (_Float16)pz[(size_t)(2 * q + 1) * HDIM];
            w2r[q] = r; w2n[q] = nn; w2z[q] = z;
        }
        #pragma unroll
        for (int q = 0; q < KPT / 2; ++q)
            asm volatile("" : "+v"(w2r[q]), "+v"(w2n[q]), "+v"(w2z[q]));
    }

    const size_t gs = (size_t)M * HDIM;
    // per-chain tag bases (chain i = batch 4g+i)
    unsigned long long* hTb[KCH];
    unsigned long long* uTb[KCH];
    #pragma unroll
    for (int i = 0; i < KCH; ++i) {
        hTb[i] = hT + (size_t)(KCH * g + i) * HDIM;
        uTb[i] = uT + (size_t)(KCH * g + i) * HDIM;
    }

    // owner-wave state: wave jw<KCH carries chain jw's own-column h in fp32
    float hcv = 0.f;
    if (jw < KCH) {
        if (t0 == 0) {
            hcv = state[(size_t)(KCH * g + jw) * HDIM + n];
        } else {
            unsigned long long v;
            do { v = loadt(hTb[jw] + n); } while ((unsigned)(v >> 32) != (unsigned)t0);
            hcv = __uint_as_float((unsigned)v);
        }
    }

    for (int tt = 0; tt < nt; ++tt) {
        const int t = t0 + tt;

        // xp prefetch: owner wave loads its chain's 3 values
        float xr = 0.f, xnn = 0.f, xz = 0.f;
        if (jw < KCH) {
            const size_t rbj = ((size_t)tt * BATCH + (KCH * g + jw)) * HDIM;
            xr  = xp[rbj + n];
            xnn = xp[gs + rbj + n];
            xz  = xp[2 * gs + rbj + n];
        }

        // ---- Phase A: acquire h for all chains (batched loads), stage ----
        if (t == 0) {
            #pragma unroll
            for (int i = 0; i < KCH; ++i)
                hlds[i][tid] = (_Float16)state[(size_t)(KCH * g + i) * HDIM + tid];
        } else {
            unsigned long long v[KCH];
            #pragma unroll
            for (int i = 0; i < KCH; ++i) v[i] = loadt(hTb[i] + tid);   // 4 in flight
            #pragma unroll
            for (int i = 0; i < KCH; ++i)
                while ((unsigned)(v[i] >> 32) != (unsigned)t) v[i] = loadt(hTb[i] + tid);
            #pragma unroll
            for (int i = 0; i < KCH; ++i)
                hlds[i][tid] = (_Float16)__uint_as_float((unsigned)v[i]);
        }
        asm volatile("s_waitcnt lgkmcnt(0)" ::: "memory");
        __builtin_amdgcn_sched_barrier(0);

        // ---- R partials for all chains over own k-range ----
        #pragma unroll
        for (int i = 0; i < KCH; ++i) {
            float a0 = 0.f, a1 = 0.f, a2 = 0.f, a3 = 0.f;
            const half8v* hp = (const half8v*)&hlds[i][jw * KPT];
            #pragma unroll
            for (int q = 0; q < KPT / 8; ++q) {
                half8v h8 = hp[q];
                half2v p0 = {h8[0], h8[1]}, p1 = {h8[2], h8[3]};
                half2v p2 = {h8[4], h8[5]}, p3 = {h8[6], h8[7]};
                a0 = dot2h(p0, w2r[4 * q + 0], a0);
                a1 = dot2h(p1, w2r[4 * q + 1], a1);
                a2 = dot2h(p2, w2r[4 * q + 2], a2);
                a3 = dot2h(p3, w2r[4 * q + 3], a3);
            }
            redR[i][jw][c] = (a0 + a1) + (a2 + a3);
        }
        __syncthreads();                               // barrier A

        // ---- owner waves publish u for their chain (parallel across waves) ----
        if (jw < KCH) {
            float s01 = redR[jw][0][c] + redR[jw][1][c];
            float s23 = redR[jw][2][c] + redR[jw][3][c];
            float s45 = redR[jw][4][c] + redR[jw][5][c];
            float s67 = redR[jw][6][c] + redR[jw][7][c];
            float sR  = (s01 + s23) + (s45 + s67);
            float R = 1.f / (1.f + __expf(-(xr + sR)));
            storet(uTb[jw] + n, hcv * R, (unsigned)(t + 1));
        }

        // ---- Phase B: acquire u for all chains (batched), stage ----
        {
            unsigned long long v[KCH];
            #pragma unroll
            for (int i = 0; i < KCH; ++i) v[i] = loadt(uTb[i] + tid);
            #pragma unroll
            for (int i = 0; i < KCH; ++i)
                while ((unsigned)(v[i] >> 32) != (unsigned)(t + 1)) v[i] = loadt(uTb[i] + tid);
            #pragma unroll
            for (int i = 0; i < KCH; ++i)
                ulds[i][tid] = (_Float16)__uint_as_float((unsigned)v[i]);
        }
        asm volatile("s_waitcnt lgkmcnt(0)" ::: "memory");
        __builtin_amdgcn_sched_barrier(0);

        // ---- N,Z partials for all chains ----
        #pragma unroll
        for (int i = 0; i < KCH; ++i) {
            float aN0 = 0.f, aN1 = 0.f, aZ0 = 0.f, aZ1 = 0.f;
            const half8v* up = (const half8v*)&ulds[i][jw * KPT];
            #pragma unroll
            for (int q = 0; q < KPT / 8; ++q) {
                half8v u8 = up[q];
                half2v p0 = {u8[0], u8[1]}, p1 = {u8[2], u8[3]};
                half2v p2 = {u8[4], u8[5]}, p3 = {u8[6], u8[7]};
                aN0 = dot2h(p0, w2n[4 * q + 0], aN0);
                aZ0 = dot2h(p0, w2z[4 * q + 0], aZ0);
                aN1 = dot2h(p1, w2n[4 * q + 1], aN1);
                aZ1 = dot2h(p1, w2z[4 * q + 1], aZ1);
                aN0 = dot2h(p2, w2n[4 * q + 2], aN0);
                aZ0 = dot2h(p2, w2z[4 * q + 2], aZ0);
                aN1 = dot2h(p3, w2n[4 * q + 3], aN1);
                aZ1 = dot2h(p3, w2z[4 * q + 3], aZ1);
            }
            redN[i][jw][c] = aN0 + aN1;
            redZ[i][jw][c] = aZ0 + aZ1;
        }
        __syncthreads();                               // barrier B

        // ---- owner waves: blend, publish h, write output ----
        if (jw < KCH) {
            float n01 = redN[jw][0][c] + redN[jw][1][c], n23 = redN[jw][2][c] + redN[jw][3][c];
            float n45 = redN[jw][4][c] + redN[jw][5][c], n67 = redN[jw][6][c] + redN[jw][7][c];
            float z01 = redZ[jw][0][c] + redZ[jw][1][c], z23 = redZ[jw][2][c] + redZ[jw][3][c];
            float z45 = redZ[jw][4][c] + redZ[jw][5][c], z67 = redZ[jw][6][c] + redZ[jw][7][c];
            float sN = (n01 + n23) + (n45 + n67);
            float sZ = (z01 + z23) + (z45 + z67);
            float e  = __expf(2.f * (xnn + sN));
            float Hc = 1.f - 2.f / (e + 1.f);
            float Z  = 1.f / (1.f + __expf(-(xz + sZ)));
            float hnew = Z * hcv + (1.f - Z) * Hc;
            storet(hTb[jw] + n, hnew, (unsigned)(t + 1));     // publish first
            const size_t orow = ((size_t)t * BATCH + (KCH * g + jw)) * HDIM + n;
            __builtin_nontemporal_store(hnew, out + orow);
            hcv = hnew;
            if (t == T_STEPS - 1)
                out[(size_t)T_STEPS * BATCH * HDIM + (size_t)(KCH * g + jw) * HDIM + n] = hnew;
        }
    }
}

extern "C" void kernel_launch(void* const* d_in, const int* in_sizes, int n_in,
                              void* d_out, int out_size, void* d_ws, size_t ws_size,
                              hipStream_t stream) {
    const float* inputs   = (const float*)d_in[0];
    const float* state    = (const float*)d_in[1];
    const float* W_reset  = (const float*)d_in[2];
    const float* b_reset  = (const float*)d_in[3];
    const float* W_net    = (const float*)d_in[4];
    const float* b_net    = (const float*)d_in[5];
    const float* W_update = (const float*)d_in[6];
    const float* b_update = (const float*)d_in[7];
    float* out = (float*)d_out;

    // ws layout: [xp chunk | packed Bt (1.5 MB) | tags (256 KB)]
    const size_t tag_bytes = 2ull * BATCH * HDIM * 8;
    const size_t bt_bytes  = 3ull * 64 * 512 * 8 * sizeof(_Float16);
    size_t tag_base = (ws_size - tag_bytes) & ~(size_t)255;
    size_t bt_base  = (tag_base - bt_bytes) & ~(size_t)255;
    char* base = (char*)d_ws;
    float*      xp = (float*)base;
    _Float16*   Bt = (_Float16*)(base + bt_base);
    unsigned long long* hT = (unsigned long long*)(base + tag_base);
    unsigned long long* uT = hT + (size_t)BATCH * HDIM;

    const size_t per_t = 3ull * BATCH * HDIM * sizeof(float);
    int C = (int)(bt_base / per_t);
    if (C > T_STEPS) C = T_STEPS;
    C &= ~3;                       // M divisible by BM=128
    if (C < 4) C = 4;

    hipMemsetAsync(hT, 0xFF, tag_bytes, stream);

    dim3 gp(64, 3);
    pack_b<<<gp, 512, 0, stream>>>(W_reset, W_net, W_update, Bt);

    for (int t0 = 0; t0 < T_STEPS; t0 += C) {
        const int nt = (T_STEPS - t0 < C) ? (T_STEPS - t0) : C;
        const int M  = nt * BATCH;

        dim3 g1(HDIM / BN, M / BM);
        xproj_mfma2<<<g1, 256, 0, stream>>>(inputs + (size_t)t0 * BATCH * VDIM,
                                            Bt, b_reset, b_net, b_update, xp, M);

        gru_scan7<<<(BATCH / KCH) * SLICES, 512, 0, stream>>>(
            xp,
            W_reset  + (size_t)VDIM * HDIM,
            W_net    + (size_t)VDIM * HDIM,
            W_update + (size_t)VDIM * HDIM,
            state, out, hT, uT, t0, nt, M);
    }
}

// Round 10
// 5371.682 us; speedup vs baseline: 2.1061x; 2.1061x over previous
//
#include <hip/hip_runtime.h>
#include <cstdint>
#include <cstddef>

#define T_STEPS 2048
#define BATCH   32
#define VDIM    512
#define HDIM    512
#define SLICES  8      // WGs per batch element (scan)
#define COLS    64     // columns per scan WG
#define KPT     64     // k-range per scan wave
#define BM      128    // GEMM rows per WG
#define BN      64     // GEMM cols per WG

typedef _Float16 half2v __attribute__((ext_vector_type(2)));
typedef _Float16 half8v __attribute__((ext_vector_type(8)));
typedef float    f32x4  __attribute__((ext_vector_type(4)));

__device__ __forceinline__ float dot2h(half2v a, half2v b, float c) {
#if __has_builtin(__builtin_amdgcn_fdot2)
    return __builtin_amdgcn_fdot2(a, b, c, false);
#else
    return fmaf((float)a.x, (float)b.x, fmaf((float)a.y, (float)b.y, c));
#endif
}

__device__ __forceinline__ unsigned long long loadt(const unsigned long long* p) {
    return __hip_atomic_load(p, __ATOMIC_RELAXED, __HIP_MEMORY_SCOPE_AGENT);
}
__device__ __forceinline__ void storet(unsigned long long* p, float v, unsigned tag) {
    unsigned long long x = ((unsigned long long)tag << 32) | (unsigned)__float_as_uint(v);
    __hip_atomic_store(p, x, __ATOMIC_RELAXED, __HIP_MEMORY_SCOPE_AGENT);
}

// ---------------- Phase 0: pack W -> k-packed f16 tiles (once per call) ----
__global__ __launch_bounds__(512)
void pack_b(const float* __restrict__ W0, const float* __restrict__ W1,
            const float* __restrict__ W2, _Float16* __restrict__ Bt)
{
    const int kg = blockIdx.x;
    const int g  = blockIdx.y;
    const float* W = (g == 0) ? W0 : (g == 1) ? W1 : W2;
    const int n = threadIdx.x;
    half8v v;
    #pragma unroll
    for (int i = 0; i < 8; ++i)
        v[i] = (_Float16)W[(size_t)(kg * 8 + i) * HDIM + n];
    *(half8v*)&Bt[((((size_t)g * 64 + kg) * 512) + n) * 8] = v;
}

// ---------------- Phase 1: fused-gate x-projection via f16 MFMA ----------
// xp stores are NON-TEMPORAL: xp is a 402 MB read-once stream with ~ms reuse
// distance; without nt it thrashes the scan's hot 256 KB tag buffer out of MALL.
__global__ __launch_bounds__(256)
void xproj_mfma2(const float* __restrict__ X, const _Float16* __restrict__ Bt,
                 const float* __restrict__ b0, const float* __restrict__ b1,
                 const float* __restrict__ b2,
                 float* __restrict__ xp, int M)
{
    const int n0 = blockIdx.x * BN;
    const int m0 = blockIdx.y * BM;

    __shared__ __align__(16) _Float16 Blds[64 * 64 * 8];

    const int tid  = threadIdx.x;
    const int lane = tid & 63;
    const int w    = tid >> 6;
    const int r16  = lane & 15;
    const int kq   = lane >> 4;

    half8v a[2][16];
    #pragma unroll
    for (int ms = 0; ms < 2; ++ms) {
        const float* ap = X + (size_t)(m0 + 32 * w + 16 * ms + r16) * VDIM;
        #pragma unroll
        for (int ks = 0; ks < 16; ++ks) {
            const float* p = ap + ks * 32 + kq * 8;
            float4 x0 = *(const float4*)p;
            float4 x1 = *(const float4*)(p + 4);
            half8v v;
            v[0] = (_Float16)x0.x; v[1] = (_Float16)x0.y;
            v[2] = (_Float16)x0.z; v[3] = (_Float16)x0.w;
            v[4] = (_Float16)x1.x; v[5] = (_Float16)x1.y;
            v[6] = (_Float16)x1.z; v[7] = (_Float16)x1.w;
            a[ms][ks] = v;
        }
    }
    #pragma unroll
    for (int ms = 0; ms < 2; ++ms)
        #pragma unroll
        for (int ks = 0; ks < 16; ++ks)
            asm volatile("" : "+v"(a[ms][ks]));

    for (int g = 0; g < 3; ++g) {
        __syncthreads();
        {
            const _Float16* src = Bt + (((size_t)g * 64) * 512 + n0) * 8;
            const int c = tid & 63;
            #pragma unroll
            for (int it = 0; it < 16; ++it) {
                const int kg = (tid >> 6) + 4 * it;
                *(half8v*)&Blds[(size_t)(kg * 64 + c) * 8] =
                    *(const half8v*)&src[((size_t)kg * 512 + c) * 8];
            }
        }
        __syncthreads();

        f32x4 acc[2][4] = {};
        #pragma unroll
        for (int ks = 0; ks < 16; ++ks) {
            #pragma unroll
            for (int cb = 0; cb < 4; ++cb) {
                half8v bf = *(const half8v*)
                    &Blds[(size_t)((4 * ks + kq) * 64 + 16 * cb + r16) * 8];
                acc[0][cb] = __builtin_amdgcn_mfma_f32_16x16x32_f16(a[0][ks], bf, acc[0][cb], 0, 0, 0);
                acc[1][cb] = __builtin_amdgcn_mfma_f32_16x16x32_f16(a[1][ks], bf, acc[1][cb], 0, 0, 0);
            }
        }

        const float* bias = (g == 0) ? b0 : (g == 1) ? b1 : b2;
        float* out = xp + (size_t)g * M * HDIM;
        #pragma unroll
        for (int cb = 0; cb < 4; ++cb) {
            const float bb = bias[n0 + 16 * cb + r16];
            #pragma unroll
            for (int ms = 0; ms < 2; ++ms)
                #pragma unroll
                for (int r = 0; r < 4; ++r) {
                    const int row = m0 + 32 * w + 16 * ms + 4 * kq + r;
                    __builtin_nontemporal_store(acc[ms][cb][r] + bb,
                        &out[(size_t)row * HDIM + n0 + 16 * cb + r16]);
                }
        }
    }
}

// ---------------- Phase 2: scan (R8 structure; xp loads non-temporal) ------
__global__ __launch_bounds__(512)
__attribute__((amdgpu_waves_per_eu(2, 2)))
void gru_scan6(const float* __restrict__ xp,
               const float* __restrict__ Wrh, const float* __restrict__ Wnh,
               const float* __restrict__ Wzh,
               const float* __restrict__ state, float* __restrict__ out,
               unsigned long long* __restrict__ hT,
               unsigned long long* __restrict__ uT,
               int t0, int nt, int M)
{
    const int b   = blockIdx.x & (BATCH - 1);
    const int s   = blockIdx.x >> 5;
    const int tid = threadIdx.x;
    const int c   = tid & (COLS - 1);
    const int j   = tid >> 6;
    const int n   = s * COLS + c;

    __shared__ __align__(16) _Float16 hlds[HDIM];
    __shared__ __align__(16) _Float16 ulds[HDIM];
    __shared__ float redR[SLICES][COLS];
    __shared__ float redN[SLICES][COLS];
    __shared__ float redZ[SLICES][COLS];

    half2v w2r[KPT / 2], w2n[KPT / 2], w2z[KPT / 2];
    {
        const size_t coloff = (size_t)s * COLS + c;
        const float* pr = Wrh + (size_t)j * KPT * HDIM + coloff;
        const float* pn = Wnh + (size_t)j * KPT * HDIM + coloff;
        const float* pz = Wzh + (size_t)j * KPT * HDIM + coloff;
        #pragma unroll
        for (int q = 0; q < KPT / 2; ++q) {
            half2v r, nn, z;
            r.x  = (_Float16)pr[(size_t)(2 * q) * HDIM];
            r.y  = (_Float16)pr[(size_t)(2 * q + 1) * HDIM];
            nn.x = (_Float16)pn[(size_t)(2 * q) * HDIM];
            nn.y = (_Float16)pn[(size_t)(2 * q + 1) * HDIM];
            z.x  = (_Float16)pz[(size_t)(2 * q) * HDIM];
            z.y  = (_Float16)pz[(size_t)(2 * q + 1) * HDIM];
            w2r[q] = r; w2n[q] = nn; w2z[q] = z;
        }
        #pragma unroll
        for (int q = 0; q < KPT / 2; ++q)
            asm volatile("" : "+v"(w2r[q]), "+v"(w2n[q]), "+v"(w2z[q]));
    }

    const size_t bb32 = (size_t)b * HDIM;
    unsigned long long* hTb = hT + bb32;
    unsigned long long* uTb = uT + bb32;
    const size_t gs = (size_t)M * HDIM;

    float hcv = 0.f;                   // wave0: own-column h, register-carried

    for (int tt = 0; tt < nt; ++tt) {
        const int t = t0 + tt;

        float xr = 0.f, xnn = 0.f, xz = 0.f;
        const size_t rb = ((size_t)tt * BATCH + b) * HDIM;
        if (tid < COLS) {
            xr  = __builtin_nontemporal_load(&xp[rb + n]);
            xnn = __builtin_nontemporal_load(&xp[gs + rb + n]);
            xz  = __builtin_nontemporal_load(&xp[2 * gs + rb + n]);
        }

        float hv;
        if (t == 0) {
            hv = state[bb32 + tid];
            if (tid < COLS) hcv = state[bb32 + n];
        } else {
            unsigned long long v;
            do { v = loadt(hTb + tid); } while ((unsigned)(v >> 32) != (unsigned)t);
            hv = __uint_as_float((unsigned)v);
            if (tt == 0 && tid < COLS) {   // chunk restart only: recover carry
                do { v = loadt(hTb + n); } while ((unsigned)(v >> 32) != (unsigned)t);
                hcv = __uint_as_float((unsigned)v);
            }
        }

        hlds[tid] = (_Float16)hv;
        asm volatile("s_waitcnt lgkmcnt(0)" ::: "memory");
        __builtin_amdgcn_sched_barrier(0);

        // ---- R partials: 4 independent acc chains of depth 8 ----
        {
            float a0 = 0.f, a1 = 0.f, a2 = 0.f, a3 = 0.f;
            const half8v* hp = (const half8v*)&hlds[j * KPT];
            #pragma unroll
            for (int q = 0; q < KPT / 8; ++q) {
                half8v h8 = hp[q];
                half2v p0 = {h8[0], h8[1]}, p1 = {h8[2], h8[3]};
                half2v p2 = {h8[4], h8[5]}, p3 = {h8[6], h8[7]};
                a0 = dot2h(p0, w2r[4 * q + 0], a0);
                a1 = dot2h(p1, w2r[4 * q + 1], a1);
                a2 = dot2h(p2, w2r[4 * q + 2], a2);
                a3 = dot2h(p3, w2r[4 * q + 3], a3);
            }
            redR[j][c] = (a0 + a1) + (a2 + a3);
        }
        __syncthreads();                               // barrier A

        if (tid < COLS) {
            float s01 = redR[0][c] + redR[1][c];
            float s23 = redR[2][c] + redR[3][c];
            float s45 = redR[4][c] + redR[5][c];
            float s67 = redR[6][c] + redR[7][c];
            float sR  = (s01 + s23) + (s45 + s67);
            float R = 1.f / (1.f + __expf(-(xr + sR)));
            storet(uTb + n, hcv * R, (unsigned)(t + 1));
        }

        {
            unsigned long long v;
            do { v = loadt(uTb + tid); } while ((unsigned)(v >> 32) != (unsigned)(t + 1));
            ulds[tid] = (_Float16)__uint_as_float((unsigned)v);
        }
        asm volatile("s_waitcnt lgkmcnt(0)" ::: "memory");
        __builtin_amdgcn_sched_barrier(0);

        // ---- N,Z partials: 2+2 acc chains of depth 16 ----
        {
            float aN0 = 0.f, aN1 = 0.f, aZ0 = 0.f, aZ1 = 0.f;
            const half8v* up = (const half8v*)&ulds[j * KPT];
            #pragma unroll
            for (int q = 0; q < KPT / 8; ++q) {
                half8v u8 = up[q];
                half2v p0 = {u8[0], u8[1]}, p1 = {u8[2], u8[3]};
                half2v p2 = {u8[4], u8[5]}, p3 = {u8[6], u8[7]};
                aN0 = dot2h(p0, w2n[4 * q + 0], aN0);
                aZ0 = dot2h(p0, w2z[4 * q + 0], aZ0);
                aN1 = dot2h(p1, w2n[4 * q + 1], aN1);
                aZ1 = dot2h(p1, w2z[4 * q + 1], aZ1);
                aN0 = dot2h(p2, w2n[4 * q + 2], aN0);
                aZ0 = dot2h(p2, w2z[4 * q + 2], aZ0);
                aN1 = dot2h(p3, w2n[4 * q + 3], aN1);
                aZ1 = dot2h(p3, w2z[4 * q + 3], aZ1);
            }
            redN[j][c] = aN0 + aN1;
            redZ[j][c] = aZ0 + aZ1;
        }
        __syncthreads();                               // barrier B

        if (tid < COLS) {
            float n01 = redN[0][c] + redN[1][c], n23 = redN[2][c] + redN[3][c];
            float n45 = redN[4][c] + redN[5][c], n67 = redN[6][c] + redN[7][c];
            float z01 = redZ[0][c] + redZ[1][c], z23 = redZ[2][c] + redZ[3][c];
            float z45 = redZ[4][c] + redZ[5][c], z67 = redZ[6][c] + redZ[7][c];
            float sN = (n01 + n23) + (n45 + n67);
            float sZ = (z01 + z23) + (z45 + z67);
            float e  = __expf(2.f * (xnn + sN));
            float Hc = 1.f - 2.f / (e + 1.f);
            float Z  = 1.f / (1.f + __expf(-(xz + sZ)));
            float hnew = Z * hcv + (1.f - Z) * Hc;
            storet(hTb + n, hnew, (unsigned)(t + 1));  // publish FIRST
            __builtin_nontemporal_store(hnew, out + (size_t)t * BATCH * HDIM + bb32 + n);
            hcv = hnew;
            if (t == T_STEPS - 1)
                out[(size_t)T_STEPS * BATCH * HDIM + bb32 + n] = hnew;
        }
    }
}

extern "C" void kernel_launch(void* const* d_in, const int* in_sizes, int n_in,
                              void* d_out, int out_size, void* d_ws, size_t ws_size,
                              hipStream_t stream) {
    const float* inputs   = (const float*)d_in[0];
    const float* state    = (const float*)d_in[1];
    const float* W_reset  = (const float*)d_in[2];
    const float* b_reset  = (const float*)d_in[3];
    const float* W_net    = (const float*)d_in[4];
    const float* b_net    = (const float*)d_in[5];
    const float* W_update = (const float*)d_in[6];
    const float* b_update = (const float*)d_in[7];
    float* out = (float*)d_out;

    // ws layout: [xp chunk | packed Bt (1.5 MB) | tags (256 KB)]
    const size_t tag_bytes = 2ull * BATCH * HDIM * 8;
    const size_t bt_bytes  = 3ull * 64 * 512 * 8 * sizeof(_Float16);
    size_t tag_base = (ws_size - tag_bytes) & ~(size_t)255;
    size_t bt_base  = (tag_base - bt_bytes) & ~(size_t)255;
    char* base = (char*)d_ws;
    float*      xp = (float*)base;
    _Float16*   Bt = (_Float16*)(base + bt_base);
    unsigned long long* hT = (unsigned long long*)(base + tag_base);
    unsigned long long* uT = hT + (size_t)BATCH * HDIM;

    const size_t per_t = 3ull * BATCH * HDIM * sizeof(float);
    int C = (int)(bt_base / per_t);
    if (C > T_STEPS) C = T_STEPS;
    C &= ~3;                       // M divisible by BM=128
    if (C < 4) C = 4;

    hipMemsetAsync(hT, 0xFF, tag_bytes, stream);

    dim3 gp(64, 3);
    pack_b<<<gp, 512, 0, stream>>>(W_reset, W_net, W_update, Bt);

    for (int t0 = 0; t0 < T_STEPS; t0 += C) {
        const int nt = (T_STEPS - t0 < C) ? (T_STEPS - t0) : C;
        const int M  = nt * BATCH;

        dim3 g1(HDIM / BN, M / BM);
        xproj_mfma2<<<g1, 256, 0, stream>>>(inputs + (size_t)t0 * BATCH * VDIM,
                                            Bt, b_reset, b_net, b_update, xp, M);

        gru_scan6<<<BATCH * SLICES, 512, 0, stream>>>(
            xp,
            W_reset  + (size_t)VDIM * HDIM,
            W_net    + (size_t)VDIM * HDIM,
            W_update + (size_t)VDIM * HDIM,
            state, out, hT, uT, t0, nt, M);
    }
}